// Round 3
// baseline (120.180 us; speedup 1.0000x reference)
//
#include <hip/hip_runtime.h>

// RetinaNet matcher: gt_boxes [B=8, G=64, 4] f32, anchors [A=120000, 4] f32.
// Outputs (concatenated in d_out, f32): matched_idxs [B,A] (as float), matched_vals [B,A].
//
// Numerics: replicate np-f32 bit-exactly. *_rn intrinsics prevent
// -ffp-contract=fast from fusing add/mul into FMA (would break the
// `quality == highest_per_gt` exact-equality recovery step). argmax
// tie-break = first (lowest g), matching np.argmax. IoU >= 0, so the
// per-gt max reduces bit-exactly via atomicMax on the uint bit pattern.
//
// R3: occupancy/ILP fix. pass1: 2 anchors/thread, 1880 blocks (was 944),
// launch_bounds(256,8) -> 8 blocks/CU. pass2: 2 anchors/thread + unroll 4
// -> 8 independent div chains/thread, LDS reads amortized over 2 anchors.

static constexpr int G = 64;

__device__ __forceinline__ float iou_f(float gx1, float gy1, float gx2, float gy2,
                                       float garea,
                                       float ax1, float ay1, float ax2, float ay2,
                                       float aarea) {
    float ltx = fmaxf(gx1, ax1);
    float lty = fmaxf(gy1, ay1);
    float rbx = fminf(gx2, ax2);
    float rby = fminf(gy2, ay2);
    float w = fmaxf(__fsub_rn(rbx, ltx), 0.0f);
    float h = fmaxf(__fsub_rn(rby, lty), 0.0f);
    float inter = __fmul_rn(w, h);
    float denom = __fsub_rn(__fadd_rn(garea, aarea), inter);
    return __fdiv_rn(inter, denom);
}

__global__ void init_hpg(unsigned int* hpg, int n) {
    int i = blockIdx.x * blockDim.x + threadIdx.x;
    if (i < n) hpg[i] = 0u;  // 0u == 0.0f bits; IoU >= 0
}

// Pass 1: highest_per_gt[b*G+g] = max over anchors of IoU (bit-exact via uint atomicMax).
// 256 threads, 2 anchors/thread (512 anchors/block). Grid: (ceil(A/512), B).
__global__ __launch_bounds__(256, 8)
void pass1_hpg(const float* __restrict__ gt,
               const float* __restrict__ anchors,
               unsigned int* __restrict__ hpg, int A) {
    const int b = blockIdx.y;
    const int t = threadIdx.x;
    __shared__ float4 sgt[G];
    __shared__ float sga[G];
    __shared__ unsigned int sred[G];
    if (t < G) {
        const float4 gb = ((const float4*)gt)[b * G + t];
        sgt[t] = gb;
        sga[t] = __fmul_rn(__fsub_rn(gb.z, gb.x), __fsub_rn(gb.w, gb.y));
        sred[t] = 0u;
    }
    __syncthreads();

    const int base = blockIdx.x * 512;
    float ax1[2], ay1[2], ax2[2], ay2[2], aar[2];
    bool val[2];
#pragma unroll
    for (int k = 0; k < 2; ++k) {
        int a = base + k * 256 + t;
        val[k] = (a < A);
        int aa = val[k] ? a : 0;
        const float4 ab = ((const float4*)anchors)[aa];
        ax1[k] = ab.x; ay1[k] = ab.y; ax2[k] = ab.z; ay2[k] = ab.w;
        aar[k] = __fmul_rn(__fsub_rn(ax2[k], ax1[k]), __fsub_rn(ay2[k], ay1[k]));
    }

#pragma unroll 2
    for (int g = 0; g < G; ++g) {
        float4 gb = sgt[g];
        float ga = sga[g];
        float m = 0.0f;
#pragma unroll
        for (int k = 0; k < 2; ++k) {
            float iou = iou_f(gb.x, gb.y, gb.z, gb.w, ga,
                              ax1[k], ay1[k], ax2[k], ay2[k], aar[k]);
            if (val[k]) m = fmaxf(m, iou);
        }
#pragma unroll
        for (int off = 32; off > 0; off >>= 1)
            m = fmaxf(m, __shfl_xor(m, off, 64));
        if ((t & 63) == 0) atomicMax(&sred[g], __float_as_uint(m));
    }
    __syncthreads();
    if (t < G) atomicMax(&hpg[b * G + t], sred[t]);
}

// Pass 2: per anchor -> max/argmax over g, thresholds, low-quality recovery, write f32.
// 256 threads, 2 anchors/thread. Grid: (ceil(A/512), B).
__global__ void pass2_match(const float* __restrict__ gt,
                            const float* __restrict__ anchors,
                            const unsigned int* __restrict__ hpg,
                            float* __restrict__ out_idx,
                            float* __restrict__ out_val, int A) {
    const int b = blockIdx.y;
    const int t = threadIdx.x;
    __shared__ float4 sgt[G];
    __shared__ float sga[G];
    __shared__ float shpg[G];
    if (t < G) {
        const float4 gb = ((const float4*)gt)[b * G + t];
        sgt[t] = gb;
        sga[t] = __fmul_rn(__fsub_rn(gb.z, gb.x), __fsub_rn(gb.w, gb.y));
        shpg[t] = __uint_as_float(hpg[b * G + t]);
    }
    __syncthreads();

    const int base = blockIdx.x * 512;
    float ax1[2], ay1[2], ax2[2], ay2[2], aar[2];
    bool val[2];
#pragma unroll
    for (int k = 0; k < 2; ++k) {
        int a = base + k * 256 + t;
        val[k] = (a < A);
        int aa = val[k] ? a : 0;
        const float4 ab = ((const float4*)anchors)[aa];
        ax1[k] = ab.x; ay1[k] = ab.y; ax2[k] = ab.z; ay2[k] = ab.w;
        aar[k] = __fmul_rn(__fsub_rn(ax2[k], ax1[k]), __fsub_rn(ay2[k], ay1[k]));
    }

    float vmax[2] = {-1.0f, -1.0f};
    int amax[2] = {0, 0};
    bool pu[2] = {false, false};
#pragma unroll 4
    for (int g = 0; g < G; ++g) {
        float4 gb = sgt[g];
        float ga = sga[g];
        float hg = shpg[g];
#pragma unroll
        for (int k = 0; k < 2; ++k) {
            float q = iou_f(gb.x, gb.y, gb.z, gb.w, ga,
                            ax1[k], ay1[k], ax2[k], ay2[k], aar[k]);
            if (q > vmax[k]) { vmax[k] = q; amax[k] = g; }  // first-max tie-break
            pu[k] = pu[k] || (q == hg);
        }
    }

#pragma unroll
    for (int k = 0; k < 2; ++k) {
        int a = base + k * 256 + t;
        if (!val[k]) continue;
        int m;
        if (pu[k]) {
            m = amax[k];                    // low-quality match recovery
        } else if (vmax[k] < 0.4f) {
            m = -1;                         // BELOW_LOW_QUALITY
        } else if (vmax[k] < 0.5f) {
            m = -2;                         // BETWEEN_THRESHOLDS
        } else {
            m = amax[k];
        }
        size_t o = (size_t)b * A + a;
        out_idx[o] = (float)m;
        out_val[o] = vmax[k];
    }
}

extern "C" void kernel_launch(void* const* d_in, const int* in_sizes, int n_in,
                              void* d_out, int out_size, void* d_ws, size_t ws_size,
                              hipStream_t stream) {
    const float* gt = (const float*)d_in[0];
    const float* anchors = (const float*)d_in[1];
    const int BG = in_sizes[0] / 4;   // B*G = 512
    const int B = BG / G;             // 8
    const int A = in_sizes[1] / 4;    // 120000

    unsigned int* hpg = (unsigned int*)d_ws;  // B*G uints = 2 KB
    float* out_idx = (float*)d_out;
    float* out_val = out_idx + (size_t)B * A;

    init_hpg<<<(BG + 255) / 256, 256, 0, stream>>>(hpg, BG);

    dim3 g1((A + 511) / 512, B);
    pass1_hpg<<<g1, 256, 0, stream>>>(gt, anchors, hpg, A);

    dim3 g2((A + 511) / 512, B);
    pass2_match<<<g2, 256, 0, stream>>>(gt, anchors, hpg, out_idx, out_val, A);
}

// Round 5
// 118.837 us; speedup vs baseline: 1.0113x; 1.0113x over previous
//
#include <hip/hip_runtime.h>

// RetinaNet matcher: gt_boxes [B=8, G=64, 4] f32, anchors [A=120000, 4] f32.
// Outputs (concatenated in d_out, f32): matched_idxs [B,A] (as float), matched_vals [B,A].
//
// Numerics: replicate np-f32 bit-exactly. R4 failed because hipcc's
// -ffp-contract=fast may fuse mul->add chains (denom = area_sum - w*h,
// area_sum = garea + aarea) into v_fma differently per kernel shape,
// breaking the `quality == highest_per_gt` exact-equality recovery.
// Fix: opaque() value barriers on every mul result (garea, aarea, inter).
// With those, no mul feeds an add/sub -> zero legal fusion sites -> every
// remaining op is a single deterministic IEEE instruction; pass1 bits ==
// pass2 bits == np bits independent of codegen context.
// argmax tie-break = first (lowest g), matching np.argmax. IoU >= 0, so
// per-gt max reduces bit-exactly via atomicMax on the uint bit pattern.
//
// Structure (R4): pass1 transposed - lane owns g (gt box in VGPRs), anchor
// index wave-uniform -> scalar K$ loads, zero LDS/shuffle in the hot loop.
// pass2 LDS-free: gt/hpg read with uniform index (-> s_load), anchors
// per-lane in VGPRs.

static constexpr int G = 64;

__device__ __forceinline__ float opaque(float x) {
    asm volatile("" : "+v"(x));  // no-op; blocks FMA contraction across x
    return x;
}

__device__ __forceinline__ float box_area(float x1, float y1, float x2, float y2) {
    return opaque(__fmul_rn(__fsub_rn(x2, x1), __fsub_rn(y2, y1)));
}

__device__ __forceinline__ float iou_f(float gx1, float gy1, float gx2, float gy2,
                                       float garea,
                                       float ax1, float ay1, float ax2, float ay2,
                                       float aarea) {
    float ltx = fmaxf(gx1, ax1);
    float lty = fmaxf(gy1, ay1);
    float rbx = fminf(gx2, ax2);
    float rby = fminf(gy2, ay2);
    float w = fmaxf(__fsub_rn(rbx, ltx), 0.0f);
    float h = fmaxf(__fsub_rn(rby, lty), 0.0f);
    float inter = opaque(__fmul_rn(w, h));
    float denom = __fsub_rn(__fadd_rn(garea, aarea), inter);  // no fusable mul feeds this
    return __fdiv_rn(inter, denom);
}

__global__ void init_hpg(unsigned int* hpg, int n) {
    int i = blockIdx.x * blockDim.x + threadIdx.x;
    if (i < n) hpg[i] = 0u;  // 0u == 0.0f bits; IoU >= 0
}

// Pass 1 (transposed): lane l handles g = l&63; each wave scans a chunk of
// anchors with a UNIFORM index (scalar K$ loads, no LDS). Per-lane running
// max, one LDS atomic per thread at the end, one global atomic per g per block.
// Block: 256 threads = 4 waves x 128 anchors = 512 anchors/block.
__global__ __launch_bounds__(256, 8)
void pass1_hpg(const float* __restrict__ gt,
               const float* __restrict__ anchors,
               unsigned int* __restrict__ hpg, int A) {
    const int b = blockIdx.y;
    const int t = threadIdx.x;
    const int g = t & 63;

    // per-lane gt box in registers
    const float4 gb = ((const float4*)gt)[b * G + g];
    const float ga = box_area(gb.x, gb.y, gb.z, gb.w);

    __shared__ unsigned int sred[G];
    if (t < G) sred[t] = 0u;
    __syncthreads();

    const int wave = t >> 6;
    const int base = blockIdx.x * 512 + wave * 128;
    const int end = (base + 128 < A) ? (base + 128) : A;

    float m = 0.0f;
#pragma unroll 4
    for (int a = base; a < end; ++a) {
        // `a` is wave-uniform -> scalar load through K$ (no LDS, no per-lane VMEM)
        const float4 ab = ((const float4*)anchors)[a];
        float aarea = box_area(ab.x, ab.y, ab.z, ab.w);
        float iou = iou_f(gb.x, gb.y, gb.z, gb.w, ga,
                          ab.x, ab.y, ab.z, ab.w, aarea);
        m = fmaxf(m, iou);
    }

    atomicMax(&sred[g], __float_as_uint(m));
    __syncthreads();
    if (t < G) atomicMax(&hpg[b * G + t], sred[t]);
}

// Pass 2: per anchor -> max/argmax over g, thresholds, low-quality recovery.
// gt box / area / hpg read with UNIFORM index from global (-> s_load);
// anchors per-lane in VGPRs. 2 anchors/thread. Grid: (ceil(A/512), B).
__global__ __launch_bounds__(256, 8)
void pass2_match(const float* __restrict__ gt,
                 const float* __restrict__ anchors,
                 const unsigned int* __restrict__ hpg,
                 float* __restrict__ out_idx,
                 float* __restrict__ out_val, int A) {
    const int b = blockIdx.y;
    const int t = threadIdx.x;

    const int base = blockIdx.x * 512;
    float ax1[2], ay1[2], ax2[2], ay2[2], aar[2];
    bool val[2];
#pragma unroll
    for (int k = 0; k < 2; ++k) {
        int a = base + k * 256 + t;
        val[k] = (a < A);
        int aa = val[k] ? a : 0;
        const float4 ab = ((const float4*)anchors)[aa];
        ax1[k] = ab.x; ay1[k] = ab.y; ax2[k] = ab.z; ay2[k] = ab.w;
        aar[k] = box_area(ab.x, ab.y, ab.z, ab.w);
    }

    const float4* gtb = (const float4*)(gt + (size_t)b * G * 4);
    const unsigned int* hpgb = hpg + b * G;

    float vmax[2] = {-1.0f, -1.0f};
    int amax[2] = {0, 0};
    bool pu[2] = {false, false};
#pragma unroll 4
    for (int g = 0; g < G; ++g) {
        const float4 gb = gtb[g];                       // uniform -> s_load
        float ga = box_area(gb.x, gb.y, gb.z, gb.w);
        float hg = __uint_as_float(hpgb[g]);            // uniform -> s_load
#pragma unroll
        for (int k = 0; k < 2; ++k) {
            float q = iou_f(gb.x, gb.y, gb.z, gb.w, ga,
                            ax1[k], ay1[k], ax2[k], ay2[k], aar[k]);
            if (q > vmax[k]) { vmax[k] = q; amax[k] = g; }  // first-max tie-break
            pu[k] = pu[k] || (q == hg);
        }
    }

#pragma unroll
    for (int k = 0; k < 2; ++k) {
        int a = base + k * 256 + t;
        if (!val[k]) continue;
        int m;
        if (pu[k]) {
            m = amax[k];                    // low-quality match recovery
        } else if (vmax[k] < 0.4f) {
            m = -1;                         // BELOW_LOW_QUALITY
        } else if (vmax[k] < 0.5f) {
            m = -2;                         // BETWEEN_THRESHOLDS
        } else {
            m = amax[k];
        }
        size_t o = (size_t)b * A + a;
        out_idx[o] = (float)m;
        out_val[o] = vmax[k];
    }
}

extern "C" void kernel_launch(void* const* d_in, const int* in_sizes, int n_in,
                              void* d_out, int out_size, void* d_ws, size_t ws_size,
                              hipStream_t stream) {
    const float* gt = (const float*)d_in[0];
    const float* anchors = (const float*)d_in[1];
    const int BG = in_sizes[0] / 4;   // B*G = 512
    const int B = BG / G;             // 8
    const int A = in_sizes[1] / 4;    // 120000

    unsigned int* hpg = (unsigned int*)d_ws;  // B*G uints = 2 KB
    float* out_idx = (float*)d_out;
    float* out_val = out_idx + (size_t)B * A;

    init_hpg<<<(BG + 255) / 256, 256, 0, stream>>>(hpg, BG);

    dim3 g1((A + 511) / 512, B);
    pass1_hpg<<<g1, 256, 0, stream>>>(gt, anchors, hpg, A);

    dim3 g2((A + 511) / 512, B);
    pass2_match<<<g2, 256, 0, stream>>>(gt, anchors, hpg, out_idx, out_val, A);
}